// Round 14
// baseline (307.884 us; speedup 1.0000x reference)
//
#include <hip/hip_runtime.h>

typedef __attribute__((ext_vector_type(8))) short short8;
typedef __attribute__((ext_vector_type(4))) float f32x4;

constexpr int T_STEPS = 32;
constexpr int BATCH   = 32;
constexpr int DG      = 256;
constexpr int DH      = 512;
constexpr int NHIST   = 31;
constexpr int LDH     = 520;   // hist_bf row stride (ushort)
constexpr int LDT     = 40;    // histT row stride (ushort)
constexpr float LAMBDA_ = 0.95f;
constexpr float ETA_    = 0.5f;
constexpr float EPS_    = 1e-5f;

__device__ __forceinline__ uint bf16cvt(float f) {
  uint u = __float_as_uint(f);
  return (u + 0x7FFFu + ((u >> 16) & 1u)) >> 16;
}
__device__ __forceinline__ uint pack2(float a, float b) {
  return bf16cvt(a) | (bf16cvt(b) << 16);
}

// pack: W_h fp32 -> bf16 MFMA A-fragment layout.
// Wp[(mt*16+kk)*64 + lane] = uint4 of 8 bf16 =
//   W[mt*16 + (lane&15)][kk*32 + (lane>>4)*8 .. +8)
__global__ __launch_bounds__(512) void pack_kernel(
    const float* __restrict__ Wh, uint4* __restrict__ Wp) {
  const int f  = blockIdx.x * 512 + threadIdx.x;   // 0..32767
  const int lf = f & 63;
  const int kk = (f >> 6) & 15;
  const int mt = f >> 10;
  const int r  = mt * 16 + (lf & 15);
  const int k0 = kk * 32 + (lf >> 4) * 8;
  const float4 a = *reinterpret_cast<const float4*>(Wh + (size_t)r * DH + k0);
  const float4 b = *reinterpret_cast<const float4*>(Wh + (size_t)r * DH + k0 + 4);
  Wp[f] = make_uint4(pack2(a.x, a.y), pack2(a.z, a.w),
                     pack2(b.x, b.y), pack2(b.z, b.w));
}

// Serial recurrence: 32 self-contained blocks x 512 threads, one batch each.
// Phase 1 streams W via global_load_lds double-buffer (no dest VGPRs ->
// unbounded pipeline depth; counted vmcnt(4), never 0 mid-loop). ZG lives in
// global (written by the MFMA prologue); history bf16 in LDS.
__global__ __launch_bounds__(512, 2) void rnn_kernel(
    const uint4* __restrict__ Wp, const float* __restrict__ z,
    const float* __restrict__ Wg, const float* __restrict__ bh,
    const float* __restrict__ g, const float* __restrict__ be,
    float* __restrict__ ZGg, float* __restrict__ out) {
  __shared__ uint4  stage[8][2][4][64];    // 64 KB: wave-private W staging
  __shared__ ushort hist_bf[NHIST][LDH];   // 31.5 KB: history rows (dots)
  __shared__ ushort histT[DH][LDT];        // 40 KB: transposed history (Ah)
  __shared__ float  part[DH];
  __shared__ float  h_s[DH];
  __shared__ ushort hbf[DH];
  __shared__ float  red1[8], red2[8];
  __shared__ float  cc[NHIST + 1];
  __shared__ float  lam_pow[NHIST];

  const int tid  = threadIdx.x;            // 0..511
  const int lane = tid & 63;
  const int wave = tid >> 6;               // 0..7
  const int c    = lane & 15;              // mfma col
  const int gq   = lane >> 4;              // mfma k-group / row-quad
  const int b    = blockIdx.x;             // batch == block
  const int r    = tid;                    // owned row

  if (tid == 0) {
    float p = 1.f;
    for (int k = 0; k < NHIST; ++k) { lam_pow[k] = p; p *= LAMBDA_; }
  }
  if (tid < NHIST + 1) cc[tid] = 0.f;      // slots >= t stay 0 -> no Ah guards
  {                                         // zero own histT row (NaN guard)
    uint4 zz = make_uint4(0u, 0u, 0u, 0u);
#pragma unroll
    for (int i = 0; i < 5; ++i)
      reinterpret_cast<uint4*>(&histT[r][0])[i] = zz;
  }

  // async stage of one kk-column (4 tiles) into stage[wave][slot]
  auto STAGE = [&](int kk, int slot) {
#pragma unroll
    for (int mt4 = 0; mt4 < 4; ++mt4) {
      const uint4* gsrc = Wp + (size_t)((wave * 4 + mt4) * 16 + kk) * 64 + lane;
      __builtin_amdgcn_global_load_lds(
          (const __attribute__((address_space(1))) uint*)gsrc,
          (__attribute__((address_space(3))) uint*)&stage[wave][slot][mt4][0],
          16, 0, 0);
    }
  };

  // ---- Prologue: ZGg[t][b][:] = z_b @ Wg^T (MFMA bf16; cols = t) ----
#pragma unroll
  for (int mt4 = 0; mt4 < 4; ++mt4) {
    const int mt = wave * 4 + mt4;          // 32 M-tiles over DH=512
    f32x4 acc0 = {0.f,0.f,0.f,0.f}, acc1 = {0.f,0.f,0.f,0.f};
#pragma unroll
    for (int kk = 0; kk < 8; ++kk) {        // K = 256
      const int k0 = kk * 32 + gq * 8;
      const float4 a  = *reinterpret_cast<const float4*>(Wg + (size_t)(mt*16 + c) * DG + k0);
      const float4 a2 = *reinterpret_cast<const float4*>(Wg + (size_t)(mt*16 + c) * DG + k0 + 4);
      const uint4 afu = make_uint4(pack2(a.x,a.y), pack2(a.z,a.w),
                                   pack2(a2.x,a2.y), pack2(a2.z,a2.w));
      const float* zb0 = z + ((size_t)c        * BATCH + b) * DG + k0;  // t = c
      const float* zb1 = z + ((size_t)(16 + c) * BATCH + b) * DG + k0;  // t = 16+c
      const float4 b00 = *reinterpret_cast<const float4*>(zb0);
      const float4 b01 = *reinterpret_cast<const float4*>(zb0 + 4);
      const float4 b10 = *reinterpret_cast<const float4*>(zb1);
      const float4 b11 = *reinterpret_cast<const float4*>(zb1 + 4);
      const uint4 bf0 = make_uint4(pack2(b00.x,b00.y), pack2(b00.z,b00.w),
                                   pack2(b01.x,b01.y), pack2(b01.z,b01.w));
      const uint4 bf1 = make_uint4(pack2(b10.x,b10.y), pack2(b10.z,b10.w),
                                   pack2(b11.x,b11.y), pack2(b11.z,b11.w));
      acc0 = __builtin_amdgcn_mfma_f32_16x16x32_bf16(
          __builtin_bit_cast(short8, afu), __builtin_bit_cast(short8, bf0), acc0, 0,0,0);
      acc1 = __builtin_amdgcn_mfma_f32_16x16x32_bf16(
          __builtin_bit_cast(short8, afu), __builtin_bit_cast(short8, bf1), acc1, 0,0,0);
    }
    // D: col=lane&15 -> t, rows mt*16 + gq*4 + 0..3
    *reinterpret_cast<f32x4*>(&ZGg[((size_t)c        * BATCH + b) * DH + mt*16 + gq*4]) = acc0;
    *reinterpret_cast<f32x4*>(&ZGg[((size_t)(16 + c) * BATCH + b) * DH + mt*16 + gq*4]) = acc1;
  }
  __syncthreads();   // compiler drains vmcnt before barrier -> ZGg visible

  const float bh_r = bh[r], g_r = g[r], be_r = be[r];

  // LayerNorm+ReLU over 512 thread-held scalars; 2 barriers; writes h_s+hbf.
  auto ln = [&](float x) -> float {
    float s1 = x, s2 = x * x;
#pragma unroll
    for (int off = 32; off; off >>= 1) {
      s1 += __shfl_xor(s1, off, 64);
      s2 += __shfl_xor(s2, off, 64);
    }
    if (lane == 0) { red1[wave] = s1; red2[wave] = s2; }
    __syncthreads();
    float a = 0.f, q = 0.f;
#pragma unroll
    for (int w2 = 0; w2 < 8; ++w2) { a += red1[w2]; q += red2[w2]; }
    const float mu = a * (1.f / DH);
    const float rs = rsqrtf(q * (1.f / DH) - mu * mu + EPS_);
    const float hv2 = fmaxf((x - mu) * rs * g_r + be_r, 0.f);
    h_s[r] = hv2;
    hbf[r] = (ushort)bf16cvt(hv2);
    __syncthreads();
    return hv2;
  };

  float hv = 0.f;
  for (int t = 0; t < T_STEPS; ++t) {
    float xb;
    if (t == 0) {
      xb = ZGg[(size_t)b * DH + r] + bh_r;   // h==0: hb = zg
    } else {
      // Phase 1: hb = Wh.h via MFMA with LDS-staged W.
      // zg first, then drain so ONLY stage loads are in the vmcnt counter.
      const float zgv = ZGg[((size_t)t * BATCH + b) * DH + r];
      asm volatile("s_waitcnt vmcnt(0)" ::: "memory");
      __builtin_amdgcn_sched_barrier(0);

      STAGE(0, 0);
      STAGE(1, 1);
      f32x4 acc[4] = {{0.f,0.f,0.f,0.f},{0.f,0.f,0.f,0.f},
                      {0.f,0.f,0.f,0.f},{0.f,0.f,0.f,0.f}};
#pragma unroll
      for (int kk = 0; kk < 16; ++kk) {
        const int slot = kk & 1;
        // oldest-4 (= this kk's tiles) complete; next kk's 4 stay in flight
        if (kk < 15) { asm volatile("s_waitcnt vmcnt(4)" ::: "memory"); }
        else         { asm volatile("s_waitcnt vmcnt(0)" ::: "memory"); }
        __builtin_amdgcn_sched_barrier(0);
        const uint4 a0 = stage[wave][slot][0][lane];
        const uint4 a1 = stage[wave][slot][1][lane];
        const uint4 a2 = stage[wave][slot][2][lane];
        const uint4 a3 = stage[wave][slot][3][lane];
        uint4 bvu = {0u,0u,0u,0u};
        if (c == 0)
          bvu = *reinterpret_cast<const uint4*>(&hbf[kk*32 + gq*8]);
        const short8 bv = __builtin_bit_cast(short8, bvu);
        acc[0] = __builtin_amdgcn_mfma_f32_16x16x32_bf16(
            __builtin_bit_cast(short8, a0), bv, acc[0], 0,0,0);
        acc[1] = __builtin_amdgcn_mfma_f32_16x16x32_bf16(
            __builtin_bit_cast(short8, a1), bv, acc[1], 0,0,0);
        acc[2] = __builtin_amdgcn_mfma_f32_16x16x32_bf16(
            __builtin_bit_cast(short8, a2), bv, acc[2], 0,0,0);
        acc[3] = __builtin_amdgcn_mfma_f32_16x16x32_bf16(
            __builtin_bit_cast(short8, a3), bv, acc[3], 0,0,0);
        if (kk < 14) STAGE(kk + 2, slot);   // refill the slot just consumed
      }
      if (c == 0) {
#pragma unroll
        for (int mt4 = 0; mt4 < 4; ++mt4)
          *reinterpret_cast<f32x4*>(&part[(wave*4 + mt4)*16 + gq*4]) = acc[mt4];
      }
      __syncthreads();                                   // B1
      xb = part[r] + zgv + bh_r;
    }

    // Phase 2: h = relu(LN(hb))
    hv = ln(xb);                                          // B2,B3

    // Phase 3: S_LOOP=2 fast-weight reads (A==0 at t=0 -> skip)
    if (t > 0) {
      for (int s = 0; s < 2; ++s) {
        // cc[sp] = ETA*lambda^(t-1-sp) * (hist[sp] . h); bf16 history rows
        const float4 c0 = *reinterpret_cast<const float4*>(&h_s[lane * 8]);
        const float4 c1 = *reinterpret_cast<const float4*>(&h_s[lane * 8 + 4]);
        for (int sp = wave; sp < t; sp += 8) {
          const uint4 hw = *reinterpret_cast<const uint4*>(&hist_bf[sp][lane * 8]);
          float d;
          d =      __uint_as_float(hw.x << 16)          * c0.x;
          d = fmaf(__uint_as_float(hw.x & 0xFFFF0000u), c0.y, d);
          d = fmaf(__uint_as_float(hw.y << 16),         c0.z, d);
          d = fmaf(__uint_as_float(hw.y & 0xFFFF0000u), c0.w, d);
          d = fmaf(__uint_as_float(hw.z << 16),         c1.x, d);
          d = fmaf(__uint_as_float(hw.z & 0xFFFF0000u), c1.y, d);
          d = fmaf(__uint_as_float(hw.w << 16),         c1.z, d);
          d = fmaf(__uint_as_float(hw.w & 0xFFFF0000u), c1.w, d);
#pragma unroll
          for (int off = 32; off; off >>= 1) d += __shfl_xor(d, off, 64);
          if (lane == 0) cc[sp] = ETA_ * lam_pow[t - 1 - sp] * d;
        }
        __syncthreads();                                  // B4
        // Ah from own-thread transposed bf16 history row: 4 x b128 + 32 fmaf
        float ah = 0.f;
#pragma unroll
        for (int q8 = 0; q8 < 4; ++q8) {
          const uint4 hw = *reinterpret_cast<const uint4*>(&histT[r][q8 * 8]);
          const uint w0 = hw.x, w1 = hw.y, w2 = hw.z, w3 = hw.w;
          ah = fmaf(cc[q8*8+0], __uint_as_float(w0 << 16),          ah);
          ah = fmaf(cc[q8*8+1], __uint_as_float(w0 & 0xFFFF0000u),  ah);
          ah = fmaf(cc[q8*8+2], __uint_as_float(w1 << 16),          ah);
          ah = fmaf(cc[q8*8+3], __uint_as_float(w1 & 0xFFFF0000u),  ah);
          ah = fmaf(cc[q8*8+4], __uint_as_float(w2 << 16),          ah);
          ah = fmaf(cc[q8*8+5], __uint_as_float(w2 & 0xFFFF0000u),  ah);
          ah = fmaf(cc[q8*8+6], __uint_as_float(w3 << 16),          ah);
          ah = fmaf(cc[q8*8+7], __uint_as_float(w3 & 0xFFFF0000u),  ah);
        }
        hv = ln(xb + ah);                                 // B5,B6
      }
    }

    // Phase 4: append history (row for dots, own transposed row for Ah)
    if (t < T_STEPS - 1) {
      const ushort hb16 = (ushort)bf16cvt(hv);
      hist_bf[t][r] = hb16;
      histT[r][t]   = hb16;
    }
  }

  out[(size_t)b * DH + r] = hv;
}

extern "C" void kernel_launch(void* const* d_in, const int* in_sizes, int n_in,
                              void* d_out, int out_size, void* d_ws, size_t ws_size,
                              hipStream_t stream) {
  const float* z     = (const float*)d_in[0];  // [T,B,DG]
  const float* W_h   = (const float*)d_in[1];  // [DH,DH]
  const float* W_g   = (const float*)d_in[2];  // [DH,DG]
  const float* b_h   = (const float*)d_in[3];  // [DH]
  const float* gamma = (const float*)d_in[4];  // [DH]
  const float* beta  = (const float*)d_in[5];  // [DH]
  float* out = (float*)d_out;                  // [B,DH]

  float* ZGg = (float*)d_ws;                                            // 2 MB
  uint4* Wp  = (uint4*)((char*)d_ws + (size_t)T_STEPS * BATCH * DH * 4); // 512 KB

  pack_kernel<<<dim3(64), dim3(512), 0, stream>>>(W_h, Wp);
  rnn_kernel<<<dim3(BATCH), dim3(512), 0, stream>>>(Wp, z, W_g, b_h,
                                                    gamma, beta, ZGg, out);
}